// Round 14
// baseline (1171.713 us; speedup 1.0000x reference)
//
#include <hip/hip_runtime.h>
#include <stdint.h>

#define B_    8
#define N_    512
#define DIN   1024
#define DOUT  1024
#define L_    16
#define T_    4096

#define BM 128
#define BN 128
#define BK 32
#define NB (DOUT / BN)          /* 8 */
#define NKT (DIN / BK)          /* 32 K-tiles */
#define MT_MAX 288
#define ZROW ((long)B_ * N_)    /* zero-row index in pooled_bf16 */

typedef __attribute__((ext_vector_type(8))) short short8;
typedef __attribute__((ext_vector_type(4))) float f32x4;

/* ws layout: pooled_bf16 (+zero row) | W' fragment-ordered bf16 | meta */
#define POOLED_ELEMS ((long)B_ * N_ * DIN + DIN)
#define WS_W_OFF     ((size_t)POOLED_ELEMS * 2)
#define WS_META_OFF  (WS_W_OFF + (size_t)L_ * DOUT * DIN * 2)

__device__ __forceinline__ unsigned short f2bf(float f) {
  unsigned u = __float_as_uint(f);
  u += 0x7FFFu + ((u >> 16) & 1u);   /* RNE */
  return (unsigned short)(u >> 16);
}

__device__ __forceinline__ void gload_lds16(const void* g, void* l) {
  __builtin_amdgcn_global_load_lds(
      (const __attribute__((address_space(1))) void*)g,
      (__attribute__((address_space(3))) void*)l, 16, 0, 0);
}

/* ---------------- kernel 1: convert pooled->bf16, W->W' fragment order ---- */
__global__ void k_convert(const float* __restrict__ pooled,
                          const float* __restrict__ W,
                          unsigned short* __restrict__ wsP,
                          unsigned short* __restrict__ wsW2) {
  const long np4 = (long)B_ * N_ * DIN / 4;
  const long nz4 = DIN / 4;
  const long nwu = (long)L_ * 64 * 32 * 64;
  long i = (long)blockIdx.x * blockDim.x + threadIdx.x;
  const long stride = (long)gridDim.x * blockDim.x;
  for (; i < np4 + nz4 + nwu; i += stride) {
    if (i < np4) {
      float4 v = ((const float4*)pooled)[i];
      ushort4 o = { f2bf(v.x), f2bf(v.y), f2bf(v.z), f2bf(v.w) };
      ((ushort4*)wsP)[i] = o;
    } else if (i < np4 + nz4) {
      ushort4 z = {0, 0, 0, 0};
      ((ushort4*)wsP)[i] = z;
    } else {
      long u = i - np4 - nz4;
      int ln = (int)(u & 63); long tmp = u >> 6;
      int kb = (int)(tmp & 31); tmp >>= 5;
      int cb = (int)(tmp & 63); int l = (int)(tmp >> 6);
      int r = cb * 16 + (ln & 15);
      int k = kb * 32 + (ln >> 4) * 8;
      const float* src = W + ((long)l * DOUT + r) * DIN + k;
      float4 v0 = *(const float4*)(src);
      float4 v1 = *(const float4*)(src + 4);
      ushort4 o0 = { f2bf(v0.x), f2bf(v0.y), f2bf(v0.z), f2bf(v0.w) };
      ushort4 o1 = { f2bf(v1.x), f2bf(v1.y), f2bf(v1.z), f2bf(v1.w) };
      ((ushort4*)wsW2)[u * 2]     = o0;
      ((ushort4*)wsW2)[u * 2 + 1] = o1;
    }
  }
}

/* ---------------- kernel 2: dedup prep (verbatim R8) ---------------- */
__global__ void k_prep(const int* __restrict__ pidx,
                       unsigned* __restrict__ tlist,
                       int* __restrict__ goff, int* __restrict__ grows,
                       unsigned* __restrict__ table, int* __restrict__ ntiles) {
  __shared__ int sp[N_];
  __shared__ int cnt[L_], pos[L_];
  const int tid = threadIdx.x;
  if (tid < N_) sp[tid] = pidx[tid];
  if (tid < L_) cnt[tid] = 0;
  __syncthreads();

  int start = tid ? sp[tid - 1] + 1 : 0;
  int len = sp[tid] - start + 1;
  if (len < 0) len = 0;
  const int nfull = len < 15 ? len : 15;

  for (int l2 = 0; l2 < nfull; ++l2) atomicAdd(&cnt[l2], 1);
  if (len > 15) atomicAdd(&cnt[15], (len - 15 + 254) / 255);
  if (tid == N_ - 1) {
    int invlen = T_ - 1 - sp[N_ - 1];
    if (invlen > 0) atomicAdd(&cnt[15], (invlen + 254) / 255);
  }
  __syncthreads();
  if (tid == 0) {
    int off = 0;
    for (int l2 = 0; l2 < L_; ++l2) {
      pos[l2] = off; goff[l2] = off; grows[l2] = cnt[l2] * B_;
      off += cnt[l2];
    }
  }
  __syncthreads();

  for (int l2 = 0; l2 < nfull; ++l2) {
    int p = atomicAdd(&pos[l2], 1);
    tlist[p] = (unsigned)(start + l2) | ((unsigned)tid << 12) | (1u << 22);
  }
  if (len > 15) {
    int rem = len - 15, tt2 = start + 15;
    while (rem > 0) {
      int rr = rem > 255 ? 255 : rem;
      int p = atomicAdd(&pos[15], 1);
      tlist[p] = (unsigned)tt2 | ((unsigned)tid << 12) | ((unsigned)rr << 22);
      tt2 += rr; rem -= rr;
    }
  }
  if (tid == N_ - 1) {
    int tt2 = sp[N_ - 1] + 1;
    int rem = T_ - tt2;
    while (rem > 0) {
      int rr = rem > 255 ? 255 : rem;
      int p = atomicAdd(&pos[15], 1);
      tlist[p] = (unsigned)tt2 | (1023u << 12) | ((unsigned)rr << 22);
      tt2 += rr; rem -= rr;
    }
  }
  __syncthreads();
  if (tid == 0) {
    int tt = 0;
    for (int l2 = 0; l2 < L_; ++l2) {
      int rows = cnt[l2] * B_;
      for (int r0 = 0; r0 < rows; r0 += BM) table[tt++] = (unsigned)l2 | ((unsigned)r0 << 4);
    }
    *ntiles = tt;
  }
}

/* ---------------- kernel 3: A-via-LDS, B-direct gather-GEMM (R10) ----------
   SINGLE CHANGE vs R10: __launch_bounds__(256,6) -> 6 blocks/CU resident
   (VGPR 76 <= 85 cap, LDS 6x16KB = 96KB). Clean A/B on TLP latency-filling. */
__global__ __launch_bounds__(256, 6)
void k_gemm(const unsigned short* __restrict__ wsP,
            const unsigned short* __restrict__ wsW2,
            const unsigned* __restrict__ tlist,
            const int* __restrict__ goff,
            const int* __restrict__ grows,
            const unsigned* __restrict__ table,
            const int* __restrict__ ntiles,
            float* __restrict__ out) {
  const int bid = blockIdx.x;
  const int mt = bid >> 3;
  const int nt = bid & 7;            /* nt == XCD: W' slice pinned per L2 */
  if (mt >= *ntiles) return;

  const unsigned te = table[mt];
  const int l    = te & 15;
  const int row0 = (int)(te >> 4);
  const int toff = goff[l];
  const int rows = grows[l];

  __shared__ __align__(16) unsigned short As[2][BM * BK];  /* 2 x 8 KiB */

  const int tid  = threadIdx.x;
  const int lane = tid & 63;
  const int w    = tid >> 6;      /* 0..3 */
  const int wm   = w >> 1;
  const int wn   = w & 1;

  /* ---- A staging (verbatim R8: inverse-swizzled source slot) ---- */
  const int srow = tid >> 2;                       /* 0..63 */
  const int sx4  = ((tid & 3) ^ ((srow >> 1) & 3)) * 16;
  const char* aptr0;
  const char* aptr1;
  {
    long re[2];
#pragma unroll
    for (int r = 0; r < 2; ++r) {
      int rg = row0 + r * 64 + srow;
      if (rg < rows) {
        unsigned e = tlist[toff + (rg >> 3)];
        unsigned n = (e >> 12) & 0x3FF;
        int b = rg & 7;
        re[r] = (n >= N_) ? ZROW * (long)DIN
                          : ((long)(b * N_ + (int)n)) * DIN;
      } else re[r] = ZROW * (long)DIN;
    }
    aptr0 = (const char*)(wsP + re[0]) + sx4;
    aptr1 = (const char*)(wsP + re[1]) + sx4;
  }

#define STG_A(t_, sb) do { \
  gload_lds16(aptr0 + (t_) * 64, (char*)As[sb] + w * 1024); \
  gload_lds16(aptr1 + (t_) * 64, (char*)As[sb] + 4096 + w * 1024); } while (0)

  /* ---- A fragment read offsets (verbatim R8, conflict-free) ---- */
  const int arow = wm * 64 + (lane & 15);
  const int axr  = ((lane >> 4) ^ (((lane & 15) >> 1) & 3)) * 16;

  /* ---- B direct: W'[l][cb][kb][lane*8], cb = nt*8 + wn*4 + n ---- */
  const unsigned short* wbase =
      wsW2 + (((long)l * 64 + nt * 8 + wn * 4) * 32) * 512 + lane * 8;
#define LDB(dst, t_) do { _Pragma("unroll") \
  for (int n_ = 0; n_ < 4; ++n_) \
    dst[n_] = *(const short8*)(wbase + n_ * (32 * 512) + (t_) * 512); } while (0)

#define DSA(bb) do { _Pragma("unroll") \
  for (int m_ = 0; m_ < 4; ++m_) \
    af[m_] = *(const short8*)((const char*)As[bb] + (arow + m_ * 16) * 64 + axr); } while (0)

#define MM(BF) do { \
  __builtin_amdgcn_s_setprio(1); \
  _Pragma("unroll") for (int n_ = 0; n_ < 4; ++n_) \
    _Pragma("unroll") for (int m_ = 0; m_ < 4; ++m_) \
      acc[m_][n_] = __builtin_amdgcn_mfma_f32_16x16x32_bf16(af[m_], BF[n_], acc[m_][n_], 0, 0, 0); \
  __builtin_amdgcn_s_setprio(0); } while (0)

  f32x4 acc[4][4];
#pragma unroll
  for (int m = 0; m < 4; ++m)
#pragma unroll
    for (int n = 0; n < 4; ++n)
      acc[m][n] = (f32x4){0.f, 0.f, 0.f, 0.f};

  short8 af[4], bf_a[4], bf_b[4];

  /* ---- prologue ---- */
  STG_A(0, 0);
  LDB(bf_a, 0);
  __syncthreads();

#pragma unroll
  for (int j = 0; j < NKT / 2; ++j) {
    const int t0 = 2 * j, t1 = 2 * j + 1;
    STG_A(t1, 1);
    LDB(bf_b, t1);
    DSA(0);
    MM(bf_a);
    __syncthreads();
    if (t0 + 2 < NKT) { STG_A(t0 + 2, 0); LDB(bf_a, t0 + 2); }
    DSA(1);
    MM(bf_b);
    __syncthreads();
  }

  /* ---- epilogue: C/D col=lane&15, row=(lane>>4)*4+j; rep-write ---- */
#pragma unroll
  for (int m = 0; m < 4; ++m) {
#pragma unroll
    for (int jj = 0; jj < 4; ++jj) {
      int rt = wm * 64 + m * 16 + (lane >> 4) * 4 + jj;
      int rg = row0 + rt;
      if (rg >= rows) continue;
      unsigned e = tlist[toff + (rg >> 3)];
      int b = rg & 7;
      int t0 = (int)(e & 0xFFFu);
      int rep = (int)(e >> 22);
      float* orow = out + ((long)b * T_ + t0) * DOUT + nt * BN + wn * 64 + (lane & 15);
      for (int r = 0; r < rep; ++r) {
#pragma unroll
        for (int n = 0; n < 4; ++n)
          orow[n * 16] = acc[m][n][jj];
        orow += DOUT;
      }
    }
  }
#undef STG_A
#undef LDB
#undef DSA
#undef MM
}

/* ---------------- launch ---------------- */
extern "C" void kernel_launch(void* const* d_in, const int* in_sizes, int n_in,
                              void* d_out, int out_size, void* d_ws, size_t ws_size,
                              hipStream_t stream) {
  const float* pooled = (const float*)d_in[0];
  const float* W      = (const float*)d_in[1];
  const int*   pidx   = (const int*)d_in[2];
  float* out = (float*)d_out;

  char* ws = (char*)d_ws;
  unsigned short* wsP  = (unsigned short*)(ws);
  unsigned short* wsW2 = (unsigned short*)(ws + WS_W_OFF);
  int* meta  = (int*)(ws + WS_META_OFF);
  unsigned* tlist = (unsigned*)meta;
  int* goff  = meta + 8 * T_;
  int* grows = meta + 8 * T_ + 16;
  unsigned* table = (unsigned*)(meta + 8 * T_ + 32);
  int* ntiles = meta + 8 * T_ + 32 + MT_MAX;

  k_prep<<<1, 512, 0, stream>>>(pidx, tlist, goff, grows, table, ntiles);
  k_convert<<<2048, 256, 0, stream>>>(pooled, W, wsP, wsW2);
  k_gemm<<<MT_MAX * NB, 256, 0, stream>>>(wsP, wsW2, tlist, goff, grows, table,
                                          ntiles, out);
}

// Round 15
// 146.292 us; speedup vs baseline: 8.0094x; 8.0094x over previous
//
#include <hip/hip_runtime.h>
#include <stdint.h>

#define B_    8
#define N_    512
#define DIN   1024
#define DOUT  1024
#define L_    16
#define T_    4096

#define BM 128
#define BN 64
#define BK 32
#define NB (DOUT / BN)          /* 16 */
#define NKT (DIN / BK)          /* 32 K-tiles */
#define MT_MAX 288
#define ZROW ((long)B_ * N_)    /* zero-row index in pooled_bf16 */

typedef __attribute__((ext_vector_type(8))) short short8;
typedef __attribute__((ext_vector_type(4))) float f32x4;

/* ws layout: pooled_bf16 (+zero row) | W' fragment-ordered bf16 | meta */
#define POOLED_ELEMS ((long)B_ * N_ * DIN + DIN)
#define WS_W_OFF     ((size_t)POOLED_ELEMS * 2)
#define WS_META_OFF  (WS_W_OFF + (size_t)L_ * DOUT * DIN * 2)

__device__ __forceinline__ unsigned short f2bf(float f) {
  unsigned u = __float_as_uint(f);
  u += 0x7FFFu + ((u >> 16) & 1u);   /* RNE */
  return (unsigned short)(u >> 16);
}

__device__ __forceinline__ void gload_lds16(const void* g, void* l) {
  __builtin_amdgcn_global_load_lds(
      (const __attribute__((address_space(1))) void*)g,
      (__attribute__((address_space(3))) void*)l, 16, 0, 0);
}

/* ---------------- kernel 1: convert pooled->bf16, W->W' fragment order ---- */
__global__ void k_convert(const float* __restrict__ pooled,
                          const float* __restrict__ W,
                          unsigned short* __restrict__ wsP,
                          unsigned short* __restrict__ wsW2) {
  const long np4 = (long)B_ * N_ * DIN / 4;
  const long nz4 = DIN / 4;
  const long nwu = (long)L_ * 64 * 32 * 64;
  long i = (long)blockIdx.x * blockDim.x + threadIdx.x;
  const long stride = (long)gridDim.x * blockDim.x;
  for (; i < np4 + nz4 + nwu; i += stride) {
    if (i < np4) {
      float4 v = ((const float4*)pooled)[i];
      ushort4 o = { f2bf(v.x), f2bf(v.y), f2bf(v.z), f2bf(v.w) };
      ((ushort4*)wsP)[i] = o;
    } else if (i < np4 + nz4) {
      ushort4 z = {0, 0, 0, 0};
      ((ushort4*)wsP)[i] = z;
    } else {
      long u = i - np4 - nz4;
      int ln = (int)(u & 63); long tmp = u >> 6;
      int kb = (int)(tmp & 31); tmp >>= 5;
      int cb = (int)(tmp & 63); int l = (int)(tmp >> 6);
      int r = cb * 16 + (ln & 15);
      int k = kb * 32 + (ln >> 4) * 8;
      const float* src = W + ((long)l * DOUT + r) * DIN + k;
      float4 v0 = *(const float4*)(src);
      float4 v1 = *(const float4*)(src + 4);
      ushort4 o0 = { f2bf(v0.x), f2bf(v0.y), f2bf(v0.z), f2bf(v0.w) };
      ushort4 o1 = { f2bf(v1.x), f2bf(v1.y), f2bf(v1.z), f2bf(v1.w) };
      ((ushort4*)wsW2)[u * 2]     = o0;
      ((ushort4*)wsW2)[u * 2 + 1] = o1;
    }
  }
}

/* ---------------- kernel 2: dedup prep (verbatim R8) ---------------- */
__global__ void k_prep(const int* __restrict__ pidx,
                       unsigned* __restrict__ tlist,
                       int* __restrict__ goff, int* __restrict__ grows,
                       unsigned* __restrict__ table, int* __restrict__ ntiles) {
  __shared__ int sp[N_];
  __shared__ int cnt[L_], pos[L_];
  const int tid = threadIdx.x;
  if (tid < N_) sp[tid] = pidx[tid];
  if (tid < L_) cnt[tid] = 0;
  __syncthreads();

  int start = tid ? sp[tid - 1] + 1 : 0;
  int len = sp[tid] - start + 1;
  if (len < 0) len = 0;
  const int nfull = len < 15 ? len : 15;

  for (int l2 = 0; l2 < nfull; ++l2) atomicAdd(&cnt[l2], 1);
  if (len > 15) atomicAdd(&cnt[15], (len - 15 + 254) / 255);
  if (tid == N_ - 1) {
    int invlen = T_ - 1 - sp[N_ - 1];
    if (invlen > 0) atomicAdd(&cnt[15], (invlen + 254) / 255);
  }
  __syncthreads();
  if (tid == 0) {
    int off = 0;
    for (int l2 = 0; l2 < L_; ++l2) {
      pos[l2] = off; goff[l2] = off; grows[l2] = cnt[l2] * B_;
      off += cnt[l2];
    }
  }
  __syncthreads();

  for (int l2 = 0; l2 < nfull; ++l2) {
    int p = atomicAdd(&pos[l2], 1);
    tlist[p] = (unsigned)(start + l2) | ((unsigned)tid << 12) | (1u << 22);
  }
  if (len > 15) {
    int rem = len - 15, tt2 = start + 15;
    while (rem > 0) {
      int rr = rem > 255 ? 255 : rem;
      int p = atomicAdd(&pos[15], 1);
      tlist[p] = (unsigned)tt2 | ((unsigned)tid << 12) | ((unsigned)rr << 22);
      tt2 += rr; rem -= rr;
    }
  }
  if (tid == N_ - 1) {
    int tt2 = sp[N_ - 1] + 1;
    int rem = T_ - tt2;
    while (rem > 0) {
      int rr = rem > 255 ? 255 : rem;
      int p = atomicAdd(&pos[15], 1);
      tlist[p] = (unsigned)tt2 | (1023u << 12) | ((unsigned)rr << 22);
      tt2 += rr; rem -= rr;
    }
  }
  __syncthreads();
  if (tid == 0) {
    int tt = 0;
    for (int l2 = 0; l2 < L_; ++l2) {
      int rows = cnt[l2] * B_;
      for (int r0 = 0; r0 < rows; r0 += BM) table[tt++] = (unsigned)l2 | ((unsigned)r0 << 4);
    }
    *ntiles = tt;
  }
}

/* ---------------- kernel 3: R10 structure, HALF wave-tile (64x32) ----------
   acc[4][2]=32 AGPR -> total regs ~90 -> 5 blocks/CU (__launch_bounds__
   (256,5)), 20 waves/CU. Clean TLP test: everything else R10-verbatim.
   Per phase: 4 ds_read + 2 B-loads + 8 MFMA, 1 barrier per K-tile.          */
__global__ __launch_bounds__(256, 5)
void k_gemm(const unsigned short* __restrict__ wsP,
            const unsigned short* __restrict__ wsW2,
            const unsigned* __restrict__ tlist,
            const int* __restrict__ goff,
            const int* __restrict__ grows,
            const unsigned* __restrict__ table,
            const int* __restrict__ ntiles,
            float* __restrict__ out) {
  const int bid = blockIdx.x;
  const int mt = bid >> 4;
  const int nt = bid & 15;           /* 64-col W' slice */
  if (mt >= *ntiles) return;

  const unsigned te = table[mt];
  const int l    = te & 15;
  const int row0 = (int)(te >> 4);
  const int toff = goff[l];
  const int rows = grows[l];

  __shared__ __align__(16) unsigned short As[2][BM * BK];  /* 2 x 8 KiB */

  const int tid  = threadIdx.x;
  const int lane = tid & 63;
  const int w    = tid >> 6;      /* 0..3 */
  const int wm   = w >> 1;        /* 0..1 : 64-row half */
  const int wn   = w & 1;         /* 0..1 : 32-col half */

  /* ---- A staging (verbatim R8: inverse-swizzled source slot) ---- */
  const int srow = tid >> 2;                       /* 0..63 */
  const int sx4  = ((tid & 3) ^ ((srow >> 1) & 3)) * 16;
  const char* aptr0;
  const char* aptr1;
  {
    long re[2];
#pragma unroll
    for (int r = 0; r < 2; ++r) {
      int rg = row0 + r * 64 + srow;
      if (rg < rows) {
        unsigned e = tlist[toff + (rg >> 3)];
        unsigned n = (e >> 12) & 0x3FF;
        int b = rg & 7;
        re[r] = (n >= N_) ? ZROW * (long)DIN
                          : ((long)(b * N_ + (int)n)) * DIN;
      } else re[r] = ZROW * (long)DIN;
    }
    aptr0 = (const char*)(wsP + re[0]) + sx4;
    aptr1 = (const char*)(wsP + re[1]) + sx4;
  }

#define STG_A(t_, sb) do { \
  gload_lds16(aptr0 + (t_) * 64, (char*)As[sb] + w * 1024); \
  gload_lds16(aptr1 + (t_) * 64, (char*)As[sb] + 4096 + w * 1024); } while (0)

  /* ---- A fragment read offsets (verbatim R8, conflict-free) ---- */
  const int arow = wm * 64 + (lane & 15);
  const int axr  = ((lane >> 4) ^ (((lane & 15) >> 1) & 3)) * 16;

  /* ---- B direct: W'[l][cb][kb][lane*8], cb = nt*4 + wn*2 + n (n<2) ---- */
  const unsigned short* wbase =
      wsW2 + (((long)l * 64 + nt * 4 + wn * 2) * 32) * 512 + lane * 8;
#define LDB(dst, t_) do { _Pragma("unroll") \
  for (int n_ = 0; n_ < 2; ++n_) \
    dst[n_] = *(const short8*)(wbase + n_ * (32 * 512) + (t_) * 512); } while (0)

#define DSA(bb) do { _Pragma("unroll") \
  for (int m_ = 0; m_ < 4; ++m_) \
    af[m_] = *(const short8*)((const char*)As[bb] + (arow + m_ * 16) * 64 + axr); } while (0)

#define MM(BF) do { \
  __builtin_amdgcn_s_setprio(1); \
  _Pragma("unroll") for (int n_ = 0; n_ < 2; ++n_) \
    _Pragma("unroll") for (int m_ = 0; m_ < 4; ++m_) \
      acc[m_][n_] = __builtin_amdgcn_mfma_f32_16x16x32_bf16(af[m_], BF[n_], acc[m_][n_], 0, 0, 0); \
  __builtin_amdgcn_s_setprio(0); } while (0)

  f32x4 acc[4][2];
#pragma unroll
  for (int m = 0; m < 4; ++m)
#pragma unroll
    for (int n = 0; n < 2; ++n)
      acc[m][n] = (f32x4){0.f, 0.f, 0.f, 0.f};

  short8 af[4], bf_a[2], bf_b[2];

  /* ---- prologue ---- */
  STG_A(0, 0);
  LDB(bf_a, 0);
  __syncthreads();

#pragma unroll
  for (int j = 0; j < NKT / 2; ++j) {
    const int t0 = 2 * j, t1 = 2 * j + 1;
    STG_A(t1, 1);
    LDB(bf_b, t1);
    DSA(0);
    MM(bf_a);
    __syncthreads();
    if (t0 + 2 < NKT) { STG_A(t0 + 2, 0); LDB(bf_a, t0 + 2); }
    DSA(1);
    MM(bf_b);
    __syncthreads();
  }

  /* ---- epilogue: C/D col=lane&15, row=(lane>>4)*4+j; rep-write ---- */
#pragma unroll
  for (int m = 0; m < 4; ++m) {
#pragma unroll
    for (int jj = 0; jj < 4; ++jj) {
      int rt = wm * 64 + m * 16 + (lane >> 4) * 4 + jj;
      int rg = row0 + rt;
      if (rg >= rows) continue;
      unsigned e = tlist[toff + (rg >> 3)];
      int b = rg & 7;
      int t0 = (int)(e & 0xFFFu);
      int rep = (int)(e >> 22);
      float* orow = out + ((long)b * T_ + t0) * DOUT + nt * BN + wn * 32 + (lane & 15);
      for (int r = 0; r < rep; ++r) {
#pragma unroll
        for (int n = 0; n < 2; ++n)
          orow[n * 16] = acc[m][n][jj];
        orow += DOUT;
      }
    }
  }
#undef STG_A
#undef LDB
#undef DSA
#undef MM
}

/* ---------------- launch ---------------- */
extern "C" void kernel_launch(void* const* d_in, const int* in_sizes, int n_in,
                              void* d_out, int out_size, void* d_ws, size_t ws_size,
                              hipStream_t stream) {
  const float* pooled = (const float*)d_in[0];
  const float* W      = (const float*)d_in[1];
  const int*   pidx   = (const int*)d_in[2];
  float* out = (float*)d_out;

  char* ws = (char*)d_ws;
  unsigned short* wsP  = (unsigned short*)(ws);
  unsigned short* wsW2 = (unsigned short*)(ws + WS_W_OFF);
  int* meta  = (int*)(ws + WS_META_OFF);
  unsigned* tlist = (unsigned*)meta;
  int* goff  = meta + 8 * T_;
  int* grows = meta + 8 * T_ + 16;
  unsigned* table = (unsigned*)(meta + 8 * T_ + 32);
  int* ntiles = meta + 8 * T_ + 32 + MT_MAX;

  k_prep<<<1, 512, 0, stream>>>(pidx, tlist, goff, grows, table, ntiles);
  k_convert<<<2048, 256, 0, stream>>>(pooled, W, wsP, wsW2);
  k_gemm<<<MT_MAX * NB, 256, 0, stream>>>(wsP, wsW2, tlist, goff, grows, table,
                                          ntiles, out);
}

// Round 16
// 130.964 us; speedup vs baseline: 8.9468x; 1.1170x over previous
//
#include <hip/hip_runtime.h>
#include <stdint.h>

#define B_    8
#define N_    512
#define DIN   1024
#define DOUT  1024
#define L_    16
#define T_    4096

#define BM 128
#define BN 128
#define BK 32
#define NB (DOUT / BN)          /* 8 */
#define NKT (DIN / BK)          /* 32 K-tiles */
#define MT_MAX 288
#define ZROW ((long)B_ * N_)    /* zero-row index in pooled_bf16 */

typedef __attribute__((ext_vector_type(8))) short short8;
typedef __attribute__((ext_vector_type(4))) float f32x4;

/* ws layout: pooled_bf16 (+zero row) | W' fragment-ordered bf16 | meta */
#define POOLED_ELEMS ((long)B_ * N_ * DIN + DIN)
#define WS_W_OFF     ((size_t)POOLED_ELEMS * 2)
#define WS_META_OFF  (WS_W_OFF + (size_t)L_ * DOUT * DIN * 2)

__device__ __forceinline__ unsigned short f2bf(float f) {
  unsigned u = __float_as_uint(f);
  u += 0x7FFFu + ((u >> 16) & 1u);   /* RNE */
  return (unsigned short)(u >> 16);
}

__device__ __forceinline__ void gload_lds16(const void* g, void* l) {
  __builtin_amdgcn_global_load_lds(
      (const __attribute__((address_space(1))) void*)g,
      (__attribute__((address_space(3))) void*)l, 16, 0, 0);
}

/* ---------------- kernel 1: convert pooled->bf16, W->W' fragment order ---- */
__global__ void k_convert(const float* __restrict__ pooled,
                          const float* __restrict__ W,
                          unsigned short* __restrict__ wsP,
                          unsigned short* __restrict__ wsW2) {
  const long np4 = (long)B_ * N_ * DIN / 4;
  const long nz4 = DIN / 4;
  const long nwu = (long)L_ * 64 * 32 * 64;
  long i = (long)blockIdx.x * blockDim.x + threadIdx.x;
  const long stride = (long)gridDim.x * blockDim.x;
  for (; i < np4 + nz4 + nwu; i += stride) {
    if (i < np4) {
      float4 v = ((const float4*)pooled)[i];
      ushort4 o = { f2bf(v.x), f2bf(v.y), f2bf(v.z), f2bf(v.w) };
      ((ushort4*)wsP)[i] = o;
    } else if (i < np4 + nz4) {
      ushort4 z = {0, 0, 0, 0};
      ((ushort4*)wsP)[i] = z;
    } else {
      long u = i - np4 - nz4;
      int ln = (int)(u & 63); long tmp = u >> 6;
      int kb = (int)(tmp & 31); tmp >>= 5;
      int cb = (int)(tmp & 63); int l = (int)(tmp >> 6);
      int r = cb * 16 + (ln & 15);
      int k = kb * 32 + (ln >> 4) * 8;
      const float* src = W + ((long)l * DOUT + r) * DIN + k;
      float4 v0 = *(const float4*)(src);
      float4 v1 = *(const float4*)(src + 4);
      ushort4 o0 = { f2bf(v0.x), f2bf(v0.y), f2bf(v0.z), f2bf(v0.w) };
      ushort4 o1 = { f2bf(v1.x), f2bf(v1.y), f2bf(v1.z), f2bf(v1.w) };
      ((ushort4*)wsW2)[u * 2]     = o0;
      ((ushort4*)wsW2)[u * 2 + 1] = o1;
    }
  }
}

/* ---------------- kernel 2: dedup prep (verbatim R8) ---------------- */
__global__ void k_prep(const int* __restrict__ pidx,
                       unsigned* __restrict__ tlist,
                       int* __restrict__ goff, int* __restrict__ grows,
                       unsigned* __restrict__ table, int* __restrict__ ntiles) {
  __shared__ int sp[N_];
  __shared__ int cnt[L_], pos[L_];
  const int tid = threadIdx.x;
  if (tid < N_) sp[tid] = pidx[tid];
  if (tid < L_) cnt[tid] = 0;
  __syncthreads();

  int start = tid ? sp[tid - 1] + 1 : 0;
  int len = sp[tid] - start + 1;
  if (len < 0) len = 0;
  const int nfull = len < 15 ? len : 15;

  for (int l2 = 0; l2 < nfull; ++l2) atomicAdd(&cnt[l2], 1);
  if (len > 15) atomicAdd(&cnt[15], (len - 15 + 254) / 255);
  if (tid == N_ - 1) {
    int invlen = T_ - 1 - sp[N_ - 1];
    if (invlen > 0) atomicAdd(&cnt[15], (invlen + 254) / 255);
  }
  __syncthreads();
  if (tid == 0) {
    int off = 0;
    for (int l2 = 0; l2 < L_; ++l2) {
      pos[l2] = off; goff[l2] = off; grows[l2] = cnt[l2] * B_;
      off += cnt[l2];
    }
  }
  __syncthreads();

  for (int l2 = 0; l2 < nfull; ++l2) {
    int p = atomicAdd(&pos[l2], 1);
    tlist[p] = (unsigned)(start + l2) | ((unsigned)tid << 12) | (1u << 22);
  }
  if (len > 15) {
    int rem = len - 15, tt2 = start + 15;
    while (rem > 0) {
      int rr = rem > 255 ? 255 : rem;
      int p = atomicAdd(&pos[15], 1);
      tlist[p] = (unsigned)tt2 | ((unsigned)tid << 12) | ((unsigned)rr << 22);
      tt2 += rr; rem -= rr;
    }
  }
  if (tid == N_ - 1) {
    int tt2 = sp[N_ - 1] + 1;
    int rem = T_ - tt2;
    while (rem > 0) {
      int rr = rem > 255 ? 255 : rem;
      int p = atomicAdd(&pos[15], 1);
      tlist[p] = (unsigned)tt2 | (1023u << 12) | ((unsigned)rr << 22);
      tt2 += rr; rem -= rr;
    }
  }
  __syncthreads();
  if (tid == 0) {
    int tt = 0;
    for (int l2 = 0; l2 < L_; ++l2) {
      int rows = cnt[l2] * B_;
      for (int r0 = 0; r0 < rows; r0 += BM) table[tt++] = (unsigned)l2 | ((unsigned)r0 << 4);
    }
    *ntiles = tt;
  }
}

/* ---------------- kernel 3: R10 + COUNTED-VMCNT barriers (T4) --------------
   Single mechanism change vs R10: raw s_barrier + hand-counted vmcnt(6)
   (never 0 until drain) so the 6 newest prefetch loads stay in flight
   ACROSS each barrier. 4 A-buffers (32 KB). Phase t:
     STG_A(t+2)->buf[(t+2)&3]; LDB(t+1); DSA(buf[t&3]); vmcnt(6);
     s_barrier; 16 MFMA.
   Entry invariant (induction-verified): STG(t) globally complete; own
   queue = [S(t+1):2, L(t):4]. vmcnt(6) forces exactly S(t+1)+L(t).        */
__global__ __launch_bounds__(256, 3)
void k_gemm(const unsigned short* __restrict__ wsP,
            const unsigned short* __restrict__ wsW2,
            const unsigned* __restrict__ tlist,
            const int* __restrict__ goff,
            const int* __restrict__ grows,
            const unsigned* __restrict__ table,
            const int* __restrict__ ntiles,
            float* __restrict__ out) {
  const int bid = blockIdx.x;
  const int mt = bid >> 3;
  const int nt = bid & 7;            /* nt == XCD: W' slice pinned per L2 */
  if (mt >= *ntiles) return;

  const unsigned te = table[mt];
  const int l    = te & 15;
  const int row0 = (int)(te >> 4);
  const int toff = goff[l];
  const int rows = grows[l];

  __shared__ __align__(16) unsigned short As[4][BM * BK];  /* 4 x 8 KiB */

  const int tid  = threadIdx.x;
  const int lane = tid & 63;
  const int w    = tid >> 6;      /* 0..3 */
  const int wm   = w >> 1;
  const int wn   = w & 1;

  /* ---- A staging (verbatim R8: inverse-swizzled source slot) ---- */
  const int srow = tid >> 2;                       /* 0..63 */
  const int sx4  = ((tid & 3) ^ ((srow >> 1) & 3)) * 16;
  const char* aptr0;
  const char* aptr1;
  {
    long re[2];
#pragma unroll
    for (int r = 0; r < 2; ++r) {
      int rg = row0 + r * 64 + srow;
      if (rg < rows) {
        unsigned e = tlist[toff + (rg >> 3)];
        unsigned n = (e >> 12) & 0x3FF;
        int b = rg & 7;
        re[r] = (n >= N_) ? ZROW * (long)DIN
                          : ((long)(b * N_ + (int)n)) * DIN;
      } else re[r] = ZROW * (long)DIN;
    }
    aptr0 = (const char*)(wsP + re[0]) + sx4;
    aptr1 = (const char*)(wsP + re[1]) + sx4;
  }

#define STG_A(t_, sb) do { \
  gload_lds16(aptr0 + (t_) * 64, (char*)As[sb] + w * 1024); \
  gload_lds16(aptr1 + (t_) * 64, (char*)As[sb] + 4096 + w * 1024); } while (0)

  /* ---- A fragment read offsets (verbatim R8, conflict-free) ---- */
  const int arow = wm * 64 + (lane & 15);
  const int axr  = ((lane >> 4) ^ (((lane & 15) >> 1) & 3)) * 16;

  /* ---- B direct: W'[l][cb][kb][lane*8], cb = nt*8 + wn*4 + n ---- */
  const unsigned short* wbase =
      wsW2 + (((long)l * 64 + nt * 8 + wn * 4) * 32) * 512 + lane * 8;
#define LDB(dst, t_) do { _Pragma("unroll") \
  for (int n_ = 0; n_ < 4; ++n_) \
    dst[n_] = *(const short8*)(wbase + n_ * (32 * 512) + (t_) * 512); } while (0)

#define DSA(bb) do { _Pragma("unroll") \
  for (int m_ = 0; m_ < 4; ++m_) \
    af[m_] = *(const short8*)((const char*)As[bb] + (arow + m_ * 16) * 64 + axr); } while (0)

#define MM(BF) do { \
  __builtin_amdgcn_s_setprio(1); \
  _Pragma("unroll") for (int n_ = 0; n_ < 4; ++n_) \
    _Pragma("unroll") for (int m_ = 0; m_ < 4; ++m_) \
      acc[m_][n_] = __builtin_amdgcn_mfma_f32_16x16x32_bf16(af[m_], BF[n_], acc[m_][n_], 0, 0, 0); \
  __builtin_amdgcn_s_setprio(0); } while (0)

  f32x4 acc[4][4];
#pragma unroll
  for (int m = 0; m < 4; ++m)
#pragma unroll
    for (int n = 0; n < 4; ++n)
      acc[m][n] = (f32x4){0.f, 0.f, 0.f, 0.f};

  short8 af[4], bf_a[4], bf_b[4];

/* phase: see header comment. VMN counted per tail analysis:
   t<=NKT-3: 6;  t==NKT-2: 4;  t==NKT-1: 0. */
#define PHASE(T, BT, BFC, BFN, VMN) do {                                      \
    if ((T) + 2 < NKT) STG_A((T) + 2, ((T) + 2) & 3);                         \
    if ((T) + 1 < NKT) LDB(BFN, (T) + 1);                                     \
    DSA(BT);                                                                  \
    asm volatile("s_waitcnt vmcnt(" #VMN ")" ::: "memory");                   \
    __builtin_amdgcn_s_barrier();                                             \
    MM(BFC);                                                                  \
  } while (0)

  /* ---- prologue: S0->buf0, S1->buf1, B(0); force S0; publish ---- */
  STG_A(0, 0);
  STG_A(1, 1);
  LDB(bf_a, 0);
  asm volatile("s_waitcnt vmcnt(6)" ::: "memory");   /* forces S0 (oldest 2) */
  __builtin_amdgcn_s_barrier();

#pragma unroll
  for (int j = 0; j < 7; ++j) {                      /* tiles 0..27 */
    const int t = 4 * j;
    PHASE(t,     0, bf_a, bf_b, 6);
    PHASE(t + 1, 1, bf_b, bf_a, 6);
    PHASE(t + 2, 2, bf_a, bf_b, 6);
    PHASE(t + 3, 3, bf_b, bf_a, 6);
  }
  PHASE(28, 0, bf_a, bf_b, 6);
  PHASE(29, 1, bf_b, bf_a, 6);
  PHASE(30, 2, bf_a, bf_b, 4);                       /* no STG(32) */
  PHASE(31, 3, bf_b, bf_a, 0);                       /* final drain */

  /* ---- epilogue: C/D col=lane&15, row=(lane>>4)*4+j; rep-write (R10) ---- */
#pragma unroll
  for (int m = 0; m < 4; ++m) {
#pragma unroll
    for (int jj = 0; jj < 4; ++jj) {
      int rt = wm * 64 + m * 16 + (lane >> 4) * 4 + jj;
      int rg = row0 + rt;
      if (rg >= rows) continue;
      unsigned e = tlist[toff + (rg >> 3)];
      int b = rg & 7;
      int t0 = (int)(e & 0xFFFu);
      int rep = (int)(e >> 22);
      float* orow = out + ((long)b * T_ + t0) * DOUT + nt * BN + wn * 64 + (lane & 15);
      for (int r = 0; r < rep; ++r) {
#pragma unroll
        for (int n = 0; n < 4; ++n)
          orow[n * 16] = acc[m][n][jj];
        orow += DOUT;
      }
    }
  }
#undef STG_A
#undef LDB
#undef DSA
#undef MM
#undef PHASE
}

/* ---------------- launch ---------------- */
extern "C" void kernel_launch(void* const* d_in, const int* in_sizes, int n_in,
                              void* d_out, int out_size, void* d_ws, size_t ws_size,
                              hipStream_t stream) {
  const float* pooled = (const float*)d_in[0];
  const float* W      = (const float*)d_in[1];
  const int*   pidx   = (const int*)d_in[2];
  float* out = (float*)d_out;

  char* ws = (char*)d_ws;
  unsigned short* wsP  = (unsigned short*)(ws);
  unsigned short* wsW2 = (unsigned short*)(ws + WS_W_OFF);
  int* meta  = (int*)(ws + WS_META_OFF);
  unsigned* tlist = (unsigned*)meta;
  int* goff  = meta + 8 * T_;
  int* grows = meta + 8 * T_ + 16;
  unsigned* table = (unsigned*)(meta + 8 * T_ + 32);
  int* ntiles = meta + 8 * T_ + 32 + MT_MAX;

  k_prep<<<1, 512, 0, stream>>>(pidx, tlist, goff, grows, table, ntiles);
  k_convert<<<2048, 256, 0, stream>>>(pooled, W, wsP, wsW2);
  k_gemm<<<MT_MAX * NB, 256, 0, stream>>>(wsP, wsW2, tlist, goff, grows, table,
                                          ntiles, out);
}

// Round 17
// 127.871 us; speedup vs baseline: 9.1632x; 1.0242x over previous
//
#include <hip/hip_runtime.h>
#include <stdint.h>

#define B_    8
#define N_    512
#define DIN   1024
#define DOUT  1024
#define L_    16
#define T_    4096

#define BM 128
#define BN 128
#define BK 32
#define NB (DOUT / BN)          /* 8 */
#define NKT (DIN / BK)          /* 32 K-tiles */
#define MT_MAX 288
#define ZROW ((long)B_ * N_)    /* zero-row index in pooled_bf16 */

typedef __attribute__((ext_vector_type(8))) short short8;
typedef __attribute__((ext_vector_type(4))) float f32x4;

/* ws layout: pooled_bf16 (+zero row) | W' fragment-ordered bf16 | meta */
#define POOLED_ELEMS ((long)B_ * N_ * DIN + DIN)
#define WS_W_OFF     ((size_t)POOLED_ELEMS * 2)
#define WS_META_OFF  (WS_W_OFF + (size_t)L_ * DOUT * DIN * 2)

__device__ __forceinline__ unsigned short f2bf(float f) {
  unsigned u = __float_as_uint(f);
  u += 0x7FFFu + ((u >> 16) & 1u);   /* RNE */
  return (unsigned short)(u >> 16);
}

__device__ __forceinline__ void gload_lds16(const void* g, void* l) {
  __builtin_amdgcn_global_load_lds(
      (const __attribute__((address_space(1))) void*)g,
      (__attribute__((address_space(3))) void*)l, 16, 0, 0);
}

/* ---------------- kernel 1: convert pooled->bf16, W->W' fragment order ------
   W'[l][cb][kb][lane*8]: lane ln holds W[l][cb*16 + (ln&15)][kb*32 + (ln>>4)*8
   .. +8) — the 16x16x32 MFMA B-fragment; a wave's B-frag load is one
   coalesced 1KB global load.                                                */
__global__ void k_convert(const float* __restrict__ pooled,
                          const float* __restrict__ W,
                          unsigned short* __restrict__ wsP,
                          unsigned short* __restrict__ wsW2) {
  const long np4 = (long)B_ * N_ * DIN / 4;
  const long nz4 = DIN / 4;
  const long nwu = (long)L_ * 64 * 32 * 64;
  long i = (long)blockIdx.x * blockDim.x + threadIdx.x;
  const long stride = (long)gridDim.x * blockDim.x;
  for (; i < np4 + nz4 + nwu; i += stride) {
    if (i < np4) {
      float4 v = ((const float4*)pooled)[i];
      ushort4 o = { f2bf(v.x), f2bf(v.y), f2bf(v.z), f2bf(v.w) };
      ((ushort4*)wsP)[i] = o;
    } else if (i < np4 + nz4) {
      ushort4 z = {0, 0, 0, 0};
      ((ushort4*)wsP)[i] = z;
    } else {
      long u = i - np4 - nz4;
      int ln = (int)(u & 63); long tmp = u >> 6;
      int kb = (int)(tmp & 31); tmp >>= 5;
      int cb = (int)(tmp & 63); int l = (int)(tmp >> 6);
      int r = cb * 16 + (ln & 15);
      int k = kb * 32 + (ln >> 4) * 8;
      const float* src = W + ((long)l * DOUT + r) * DIN + k;
      float4 v0 = *(const float4*)(src);
      float4 v1 = *(const float4*)(src + 4);
      ushort4 o0 = { f2bf(v0.x), f2bf(v0.y), f2bf(v0.z), f2bf(v0.w) };
      ushort4 o1 = { f2bf(v1.x), f2bf(v1.y), f2bf(v1.z), f2bf(v1.w) };
      ((ushort4*)wsW2)[u * 2]     = o0;
      ((ushort4*)wsW2)[u * 2 + 1] = o1;
    }
  }
}

/* ---------------- kernel 2: dedup prep (verbatim R8) ---------------- */
__global__ void k_prep(const int* __restrict__ pidx,
                       unsigned* __restrict__ tlist,
                       int* __restrict__ goff, int* __restrict__ grows,
                       unsigned* __restrict__ table, int* __restrict__ ntiles) {
  __shared__ int sp[N_];
  __shared__ int cnt[L_], pos[L_];
  const int tid = threadIdx.x;
  if (tid < N_) sp[tid] = pidx[tid];
  if (tid < L_) cnt[tid] = 0;
  __syncthreads();

  int start = tid ? sp[tid - 1] + 1 : 0;
  int len = sp[tid] - start + 1;
  if (len < 0) len = 0;
  const int nfull = len < 15 ? len : 15;

  for (int l2 = 0; l2 < nfull; ++l2) atomicAdd(&cnt[l2], 1);
  if (len > 15) atomicAdd(&cnt[15], (len - 15 + 254) / 255);
  if (tid == N_ - 1) {
    int invlen = T_ - 1 - sp[N_ - 1];
    if (invlen > 0) atomicAdd(&cnt[15], (invlen + 254) / 255);
  }
  __syncthreads();
  if (tid == 0) {
    int off = 0;
    for (int l2 = 0; l2 < L_; ++l2) {
      pos[l2] = off; goff[l2] = off; grows[l2] = cnt[l2] * B_;
      off += cnt[l2];
    }
  }
  __syncthreads();

  for (int l2 = 0; l2 < nfull; ++l2) {
    int p = atomicAdd(&pos[l2], 1);
    tlist[p] = (unsigned)(start + l2) | ((unsigned)tid << 12) | (1u << 22);
  }
  if (len > 15) {
    int rem = len - 15, tt2 = start + 15;
    while (rem > 0) {
      int rr = rem > 255 ? 255 : rem;
      int p = atomicAdd(&pos[15], 1);
      tlist[p] = (unsigned)tt2 | ((unsigned)tid << 12) | ((unsigned)rr << 22);
      tt2 += rr; rem -= rr;
    }
  }
  if (tid == N_ - 1) {
    int tt2 = sp[N_ - 1] + 1;
    int rem = T_ - tt2;
    while (rem > 0) {
      int rr = rem > 255 ? 255 : rem;
      int p = atomicAdd(&pos[15], 1);
      tlist[p] = (unsigned)tt2 | (1023u << 12) | ((unsigned)rr << 22);
      tt2 += rr; rem -= rr;
    }
  }
  __syncthreads();
  if (tid == 0) {
    int tt = 0;
    for (int l2 = 0; l2 < L_; ++l2) {
      int rows = cnt[l2] * B_;
      for (int r0 = 0; r0 < rows; r0 += BM) table[tt++] = (unsigned)l2 | ((unsigned)r0 << 4);
    }
    *ntiles = tt;
  }
}

/* ---------------- kernel 3: A-via-LDS, B-direct gather-GEMM (best: R11) ----
   128x128 tile, BK=32, 4 waves (2x2), wave 64x64. A (gathered) staged via
   gload_lds into 2x8KB LDS (verified swizzle); B loaded coalesced from W'
   straight to registers. One compiler-drained barrier per K-tile; full-line
   epilogue stores via padded LDS transpose (no RFO). 3 blocks/CU.           */
__global__ __launch_bounds__(256, 3)
void k_gemm(const unsigned short* __restrict__ wsP,
            const unsigned short* __restrict__ wsW2,
            const unsigned* __restrict__ tlist,
            const int* __restrict__ goff,
            const int* __restrict__ grows,
            const unsigned* __restrict__ table,
            const int* __restrict__ ntiles,
            float* __restrict__ out) {
  const int bid = blockIdx.x;
  const int mt = bid >> 3;
  const int nt = bid & 7;            /* nt == XCD: W' slice pinned per L2 */
  if (mt >= *ntiles) return;

  const unsigned te = table[mt];
  const int l    = te & 15;
  const int row0 = (int)(te >> 4);
  const int toff = goff[l];
  const int rows = grows[l];

  __shared__ __align__(16) unsigned short As[2][BM * BK];  /* 2 x 8 KiB */
  __shared__ __align__(16) float escr[4][16 * 68];         /* 17 KiB epi scratch */

  const int tid  = threadIdx.x;
  const int lane = tid & 63;
  const int w    = tid >> 6;      /* 0..3 */
  const int wm   = w >> 1;
  const int wn   = w & 1;

  /* ---- A staging (verbatim R8: inverse-swizzled source slot) ---- */
  const int srow = tid >> 2;                       /* 0..63 */
  const int sx4  = ((tid & 3) ^ ((srow >> 1) & 3)) * 16;
  const char* aptr0;
  const char* aptr1;
  {
    long re[2];
#pragma unroll
    for (int r = 0; r < 2; ++r) {
      int rg = row0 + r * 64 + srow;
      if (rg < rows) {
        unsigned e = tlist[toff + (rg >> 3)];
        unsigned n = (e >> 12) & 0x3FF;
        int b = rg & 7;
        re[r] = (n >= N_) ? ZROW * (long)DIN
                          : ((long)(b * N_ + (int)n)) * DIN;
      } else re[r] = ZROW * (long)DIN;
    }
    aptr0 = (const char*)(wsP + re[0]) + sx4;
    aptr1 = (const char*)(wsP + re[1]) + sx4;
  }

#define STG_A(t_, sb) do { \
  gload_lds16(aptr0 + (t_) * 64, (char*)As[sb] + w * 1024); \
  gload_lds16(aptr1 + (t_) * 64, (char*)As[sb] + 4096 + w * 1024); } while (0)

  /* ---- A fragment read offsets (verbatim R8, conflict-free) ---- */
  const int arow = wm * 64 + (lane & 15);
  const int axr  = ((lane >> 4) ^ (((lane & 15) >> 1) & 3)) * 16;

  /* ---- B direct: W'[l][cb][kb][lane*8], cb = nt*8 + wn*4 + n ---- */
  const unsigned short* wbase =
      wsW2 + (((long)l * 64 + nt * 8 + wn * 4) * 32) * 512 + lane * 8;
#define LDB(dst, t_) do { _Pragma("unroll") \
  for (int n_ = 0; n_ < 4; ++n_) \
    dst[n_] = *(const short8*)(wbase + n_ * (32 * 512) + (t_) * 512); } while (0)

#define DSA(bb) do { _Pragma("unroll") \
  for (int m_ = 0; m_ < 4; ++m_) \
    af[m_] = *(const short8*)((const char*)As[bb] + (arow + m_ * 16) * 64 + axr); } while (0)

#define MM(BF) do { \
  __builtin_amdgcn_s_setprio(1); \
  _Pragma("unroll") for (int n_ = 0; n_ < 4; ++n_) \
    _Pragma("unroll") for (int m_ = 0; m_ < 4; ++m_) \
      acc[m_][n_] = __builtin_amdgcn_mfma_f32_16x16x32_bf16(af[m_], BF[n_], acc[m_][n_], 0, 0, 0); \
  __builtin_amdgcn_s_setprio(0); } while (0)

  f32x4 acc[4][4];
#pragma unroll
  for (int m = 0; m < 4; ++m)
#pragma unroll
    for (int n = 0; n < 4; ++n)
      acc[m][n] = (f32x4){0.f, 0.f, 0.f, 0.f};

  short8 af[4], bf_a[4], bf_b[4];

  /* ---- prologue ---- */
  STG_A(0, 0);
  LDB(bf_a, 0);
  __syncthreads();

#pragma unroll
  for (int j = 0; j < NKT / 2; ++j) {
    const int t0 = 2 * j, t1 = 2 * j + 1;
    STG_A(t1, 1);
    LDB(bf_b, t1);
    DSA(0);
    MM(bf_a);
    __syncthreads();
    if (t0 + 2 < NKT) { STG_A(t0 + 2, 0); LDB(bf_a, t0 + 2); }
    DSA(1);
    MM(bf_b);
    __syncthreads();
  }

  /* ---- epilogue: full-line coalesced stores via LDS transpose ----
     Per wave, per m: scatter 16x64 acc slab into padded scratch
     (stride 68 dwords), read back 4 rows/instr as lane-contiguous 16B,
     store global_store_dwordx4: 4 x 256B full lines per instruction.
     rep>1 rows stream contiguously t..t+rep-1.                        */
  {
    float* sc = escr[w];
#pragma unroll
    for (int m = 0; m < 4; ++m) {
#pragma unroll
      for (int n = 0; n < 4; ++n)
#pragma unroll
        for (int jj = 0; jj < 4; ++jj)
          sc[((lane >> 4) * 4 + jj) * 68 + n * 16 + (lane & 15)] = acc[m][n][jj];
      asm volatile("s_waitcnt lgkmcnt(0)" ::: "memory");
#pragma unroll
      for (int r0 = 0; r0 < 16; r0 += 4) {
        int rtl = r0 + (lane >> 4);
        float4 v = *(const float4*)(sc + rtl * 68 + (lane & 15) * 4);
        int rg = row0 + wm * 64 + m * 16 + rtl;
        if (rg < rows) {
          unsigned e = tlist[toff + (rg >> 3)];
          int b = rg & 7;
          int tt = (int)(e & 0xFFFu);
          int rep = (int)(e >> 22);
          float* p = out + ((long)b * T_ + tt) * DOUT + nt * BN + wn * 64 + (lane & 15) * 4;
          for (int r = 0; r < rep; ++r) { *(float4*)p = v; p += DOUT; }
        }
      }
      asm volatile("s_waitcnt lgkmcnt(0)" ::: "memory");
    }
  }
#undef STG_A
#undef LDB
#undef DSA
#undef MM
}

/* ---------------- launch ---------------- */
extern "C" void kernel_launch(void* const* d_in, const int* in_sizes, int n_in,
                              void* d_out, int out_size, void* d_ws, size_t ws_size,
                              hipStream_t stream) {
  const float* pooled = (const float*)d_in[0];
  const float* W      = (const float*)d_in[1];
  const int*   pidx   = (const int*)d_in[2];
  float* out = (float*)d_out;

  char* ws = (char*)d_ws;
  unsigned short* wsP  = (unsigned short*)(ws);
  unsigned short* wsW2 = (unsigned short*)(ws + WS_W_OFF);
  int* meta  = (int*)(ws + WS_META_OFF);
  unsigned* tlist = (unsigned*)meta;
  int* goff  = meta + 8 * T_;
  int* grows = meta + 8 * T_ + 16;
  unsigned* table = (unsigned*)(meta + 8 * T_ + 32);
  int* ntiles = meta + 8 * T_ + 32 + MT_MAX;

  k_prep<<<1, 512, 0, stream>>>(pidx, tlist, goff, grows, table, ntiles);
  k_convert<<<2048, 256, 0, stream>>>(pooled, W, wsP, wsW2);
  k_gemm<<<MT_MAX * NB, 256, 0, stream>>>(wsP, wsW2, tlist, goff, grows, table,
                                          ntiles, out);
}